// Round 5
// baseline (218.349 us; speedup 1.0000x reference)
//
#include <hip/hip_runtime.h>

// YOLO loss: preds (B,7,7,30) f32, labels (B,7,7,30) f32 -> scalar f32 (sum/B).
// R5: no LDS staging. One thread per cell, ALL 31 loads issued back-to-back
// into distinct VGPRs before any use (memory-level parallelism). Theory:
// R1-R4 were outstanding-request starved (~4 loads in flight/CU); forcing
// ~30 in flight per wave at ~16 waves/CU covers the ~900cyc latency.

#define BATCH 16384
#define S 7
#define C 30
#define NCELLS (BATCH * S * S)   // 802816
#define BLOCK 256
#define NBLK (NCELLS / BLOCK)     // 3136

__device__ __forceinline__ float sq(float v) { return v * v; }

__device__ __forceinline__ float iou_box(float acx, float acy, float aw, float ah,
                                         float bcx, float bcy, float bw, float bh) {
    float ax0 = acx - aw * 0.5f, ax1 = acx + aw * 0.5f;
    float ay0 = acy - ah * 0.5f, ay1 = acy + ah * 0.5f;
    float bx0 = bcx - bw * 0.5f, bx1 = bcx + bw * 0.5f;
    float by0 = bcy - bh * 0.5f, by1 = bcy + bh * 0.5f;
    float iw = fmaxf(fminf(ax1, bx1) - fmaxf(ax0, bx0), 0.0f);
    float ih = fmaxf(fminf(ay1, by1) - fmaxf(ay0, by0), 0.0f);
    float inter = iw * ih;
    float denom = aw * ah + bw * bh - inter + 1e-10f;
    return inter / denom;
}

__global__ __launch_bounds__(BLOCK, 2) void yolo_partial_kernel(
        const float* __restrict__ preds,
        const float* __restrict__ labels,
        float* __restrict__ partials) {
    const int tid  = threadIdx.x;
    const int cell = blockIdx.x * BLOCK + tid;

    // transposed label x-coord quirk: labels[b, x, y, 0]
    int b    = cell / (S * S);
    int rem  = cell - b * (S * S);
    int y    = rem / S;
    int x    = rem - y * S;
    int pc   = b * (S * S) + x * S + y;       // partner cell index

    const float2* pG = reinterpret_cast<const float2*>(preds  + (size_t)cell * C);
    const float2* lG = reinterpret_cast<const float2*>(labels + (size_t)cell * C);

    // ---- issue ALL loads before any use: 15 + 15 float2 + 1 scalar ----
    float2 tp[15], tl[15];
    #pragma unroll
    for (int i = 0; i < 15; ++i) tp[i] = pG[i];
    #pragma unroll
    for (int i = 0; i < 15; ++i) tl[i] = lG[i];
    float lb0 = labels[(size_t)pc * C];

    float pv[C], lv[C];
    #pragma unroll
    for (int i = 0; i < 15; ++i) {
        pv[2 * i] = tp[i].x; pv[2 * i + 1] = tp[i].y;
        lv[2 * i] = tl[i].x; lv[2 * i + 1] = tl[i].y;
    }

    float iou1 = iou_box(pv[0], pv[1], pv[2], pv[3], lb0, lv[1], lv[2], lv[3]);
    float iou2 = iou_box(pv[5], pv[6], pv[7], pv[8], lb0, lv[1], lv[2], lv[3]);

    float b1 = 5.0f * (sq(pv[0] - lv[0]) + sq(pv[1] - lv[1]))
             + sq(sqrtf(pv[2]) - sqrtf(lv[2])) + sq(sqrtf(pv[3]) - sqrtf(lv[3]))
             + sq(iou1 - pv[4])
             + 0.5f * pv[9] * pv[9];

    float b2 = 5.0f * (sq(pv[5] - lv[5]) + sq(pv[6] - lv[6]))
             + sq(sqrtf(pv[7]) - sqrtf(lv[7])) + sq(sqrtf(pv[8]) - sqrtf(lv[8]))
             + sq(iou2 - pv[9])
             + 0.5f * pv[4] * pv[4];

    float cls = 0.0f;
    #pragma unroll
    for (int c = 10; c < C; ++c) cls += sq(lv[c] - pv[c]);

    float obj_loss   = ((iou1 > iou2) ? b1 : b2) + cls;
    float noobj_loss = 0.5f * (pv[4] * pv[4] + pv[9] * pv[9]);
    float loss = (lv[4] == 1.0f) ? obj_loss : noobj_loss;

    // ---- reduction: wave shuffle -> LDS -> one store per block ----
    #pragma unroll
    for (int off = 32; off > 0; off >>= 1)
        loss += __shfl_down(loss, off, 64);

    __shared__ float wsum[BLOCK / 64];
    int lane = tid & 63;
    int wv   = tid >> 6;
    if (lane == 0) wsum[wv] = loss;
    __syncthreads();
    if (tid == 0) {
        partials[blockIdx.x] = wsum[0] + wsum[1] + wsum[2] + wsum[3];
    }
}

__global__ __launch_bounds__(BLOCK) void yolo_reduce_kernel(
        const float* __restrict__ partials,
        float* __restrict__ out) {
    const int tid = threadIdx.x;
    float s = 0.0f;
    for (int i = tid; i < NBLK; i += BLOCK) s += partials[i];

    #pragma unroll
    for (int off = 32; off > 0; off >>= 1)
        s += __shfl_down(s, off, 64);

    __shared__ float wsum[BLOCK / 64];
    int lane = tid & 63;
    int wv   = tid >> 6;
    if (lane == 0) wsum[wv] = s;
    __syncthreads();
    if (tid == 0) {
        out[0] = (wsum[0] + wsum[1] + wsum[2] + wsum[3]) * (1.0f / (float)BATCH);
    }
}

extern "C" void kernel_launch(void* const* d_in, const int* in_sizes, int n_in,
                              void* d_out, int out_size, void* d_ws, size_t ws_size,
                              hipStream_t stream) {
    const float* preds  = (const float*)d_in[0];
    const float* labels = (const float*)d_in[1];
    float* out = (float*)d_out;
    float* partials = (float*)d_ws;   // NBLK floats = 12.25 KB

    yolo_partial_kernel<<<NBLK, BLOCK, 0, stream>>>(preds, labels, partials);
    yolo_reduce_kernel<<<1, BLOCK, 0, stream>>>(partials, out);
}